// Round 3
// baseline (219.278 us; speedup 1.0000x reference)
//
#include <hip/hip_runtime.h>
#include <math.h>

typedef __attribute__((ext_vector_type(8))) short s16x8;
typedef __attribute__((ext_vector_type(4))) short s16x4;
typedef __attribute__((ext_vector_type(4))) float f32x4;

static __device__ __forceinline__ short f2bf(float f) {
  union { float f; unsigned u; } c; c.f = f;
  unsigned u = c.u;
  unsigned r = (u + 0x7fffu + ((u >> 16) & 1u)) >> 16;  // RNE; exact for our ints
  return (short)r;
}

// ---------------- weight quantization ----------------
__global__ void kWabs(const float* __restrict__ w, int n, double* __restrict__ part) {
  int t = blockIdx.x * 256 + threadIdx.x;
  double s = 0.0;
  for (int i = t; i < n; i += 65536) s += (double)fabsf(w[i]);
#pragma unroll
  for (int m = 32; m >= 1; m >>= 1) s += __shfl_xor(s, m);
  __shared__ double sd[4];
  int lane = threadIdx.x & 63, wid = threadIdx.x >> 6;
  if (lane == 0) sd[wid] = s;
  __syncthreads();
  if (threadIdx.x == 0) part[blockIdx.x] = (sd[0] + sd[1]) + (sd[2] + sd[3]);
}

__global__ void kWfin(const double* __restrict__ p1, const double* __restrict__ p2,
                      float* __restrict__ wsv) {
  const double* p = (blockIdx.x == 0) ? p1 : p2;
  const double n = (blockIdx.x == 0) ? 524288.0 : 262144.0;
  double s = p[threadIdx.x];
#pragma unroll
  for (int m = 32; m >= 1; m >>= 1) s += __shfl_xor(s, m);
  __shared__ double sd[4];
  int lane = threadIdx.x & 63, wid = threadIdx.x >> 6;
  if (lane == 0) sd[wid] = s;
  __syncthreads();
  if (threadIdx.x == 0) {
    double tot = (sd[0] + sd[1]) + (sd[2] + sd[3]);
    wsv[blockIdx.x] = fmaxf((float)(tot / n), 1e-5f);  // = 1/scale_w
  }
}

__global__ void kWq(const float* __restrict__ w, int n, const float* __restrict__ wsv,
                    short* __restrict__ wq) {
  int i = blockIdx.x * 256 + threadIdx.x;
  if (i >= n) return;
  float scale = 1.0f / wsv[0];
  float q = fminf(fmaxf(rintf(w[i] * scale), -1.0f), 1.0f);
  wq[i] = f2bf(q);
}

// ---------------- input RMSNorm + activation quant (concat prior||evidence) ----------------
__global__ void kQ1(const float* __restrict__ prior, const float* __restrict__ evid,
                    short* __restrict__ Xq, float* __restrict__ rAct) {
  const int row = blockIdx.x;            // token index in [0, 32768)
  const int t = threadIdx.x;             // 256 threads, 4 f32 each
  const f32x4* src = (t < 128) ? (const f32x4*)(prior + (size_t)row * 512)
                               : (const f32x4*)(evid + (size_t)row * 512);
  f32x4 x = src[t & 127];
  float ss = 0.f, mx = 0.f;
#pragma unroll
  for (int i = 0; i < 4; ++i) { ss += x[i] * x[i]; mx = fmaxf(mx, fabsf(x[i])); }
#pragma unroll
  for (int m = 32; m >= 1; m >>= 1) { ss += __shfl_xor(ss, m); mx = fmaxf(mx, __shfl_xor(mx, m)); }
  __shared__ float sss[4], smx[4];
  const int lane = t & 63, wid = t >> 6;
  if (lane == 0) { sss[wid] = ss; smx[wid] = mx; }
  __syncthreads();
  ss = (sss[0] + sss[1]) + (sss[2] + sss[3]);
  mx = fmaxf(fmaxf(smx[0], smx[1]), fmaxf(smx[2], smx[3]));
  const float inv = 1.0f / sqrtf(ss * (1.0f / 1024.0f) + 1e-6f);
  const float amax = fmaxf(mx * inv, 1e-5f);
  const float s = 127.0f / amax;
  s16x4 q;
#pragma unroll
  for (int i = 0; i < 4; ++i) {
    float xn = x[i] * inv;
    q[i] = f2bf(fminf(fmaxf(rintf(xn * s), -128.0f), 127.0f));
  }
  *(s16x4*)(Xq + (size_t)row * 1024 + t * 4) = q;
  if (t == 0) rAct[row] = amax / 127.0f;
}

// ---------------- fused BitLinear GEMM (64 x 512 tile, full N) ----------------
// L1: +ReLU +row-RMSNorm +requant -> bf16 int X2q, r2
// L2: +sigmoid, *prior, write unnormalized posterior + per-block col sums
template <int KT, bool L1>
__global__ __launch_bounds__(512, 4) void kGemm(
    const short* __restrict__ Xq, const short* __restrict__ Wq,
    const float* __restrict__ biasG, const float* __restrict__ rAct,
    const float* __restrict__ wS,
    short* __restrict__ XqOut, float* __restrict__ rActOut,
    const float* __restrict__ prior, float* __restrict__ outUn,
    float* __restrict__ partG) {
  constexpr int K = KT * 32;
  __shared__ __align__(16) union {
    struct { short A[64][40]; short B[512][40]; } st;           // staging (pitch 40: 2-way reads)
    struct { short outT[64][528]; float sq[64][4]; float mx[64][4]; } ep;  // epilogue
  } u;
  __shared__ float rowR[64];
  __shared__ float biasS[512];
  __shared__ float normPart[512];

  const int tid = threadIdx.x;
  const int lane = tid & 63;
  const int wid = tid >> 6;
  const int wm = wid >> 2;   // 0..1 : 32-row strip
  const int wn = wid & 3;    // 0..3 : 128-col strip
  const int lr = lane & 15;
  const int kg = lane >> 4;  // 0..3
  const size_t row0 = (size_t)blockIdx.x * 64;

  if (tid < 64) rowR[tid] = rAct[row0 + tid];
  biasS[tid] = biasG[tid];
  if constexpr (!L1) normPart[tid] = 0.0f;

  f32x4 acc[2][8];
#pragma unroll
  for (int a = 0; a < 2; ++a)
#pragma unroll
    for (int b = 0; b < 8; ++b) acc[a][b] = (f32x4){0.f, 0.f, 0.f, 0.f};

  for (int kt = 0; kt < KT; ++kt) {
    const int k0 = kt * 32;
    {  // B tile: 512 rows of W (row n holds W[n][k0..k0+31])
      const s16x8* src = (const s16x8*)(Wq + (size_t)tid * K + k0);
      s16x8 w0 = src[0], w1 = src[1], w2 = src[2], w3 = src[3];
      s16x8* dst = (s16x8*)&u.st.B[tid][0];
      dst[0] = w0; dst[1] = w1; dst[2] = w2; dst[3] = w3;
    }
    if (tid < 64) {  // A tile: 64 token rows
      const s16x8* src = (const s16x8*)(Xq + (row0 + tid) * K + k0);
      s16x8 a0 = src[0], a1 = src[1], a2 = src[2], a3 = src[3];
      s16x8* dst = (s16x8*)&u.st.A[tid][0];
      dst[0] = a0; dst[1] = a1; dst[2] = a2; dst[3] = a3;
    }
    __syncthreads();
    // A frag: lane holds A[row=lr][k = kg*8 + j]; B frag: B[k][col=lr]
    s16x8 af0 = *(const s16x8*)&u.st.A[wm * 32 + lr][kg * 8];
    s16x8 af1 = *(const s16x8*)&u.st.A[wm * 32 + 16 + lr][kg * 8];
#pragma unroll
    for (int fn = 0; fn < 8; ++fn) {
      s16x8 bf = *(const s16x8*)&u.st.B[wn * 128 + fn * 16 + lr][kg * 8];
      acc[0][fn] = __builtin_amdgcn_mfma_f32_16x16x32_bf16(af0, bf, acc[0][fn], 0, 0, 0);
      acc[1][fn] = __builtin_amdgcn_mfma_f32_16x16x32_bf16(af1, bf, acc[1][fn], 0, 0, 0);
    }
    __syncthreads();
  }

  // ---- epilogue: dequant + bias (acc element j -> local row wm*32+fm*16+kg*4+j, col wn*128+fn*16+lr)
  const float wsv = wS[0];
  float rr[2][4];
#pragma unroll
  for (int fm = 0; fm < 2; ++fm)
#pragma unroll
    for (int j = 0; j < 4; ++j) rr[fm][j] = rowR[wm * 32 + fm * 16 + kg * 4 + j] * wsv;

#pragma unroll
  for (int fm = 0; fm < 2; ++fm)
#pragma unroll
    for (int fn = 0; fn < 8; ++fn) {
      const float bb = biasS[wn * 128 + fn * 16 + lr];
#pragma unroll
      for (int j = 0; j < 4; ++j) {
        float v = acc[fm][fn][j] * rr[fm][j] + bb;
        acc[fm][fn][j] = L1 ? fmaxf(v, 0.0f) : v;
      }
    }

  if constexpr (L1) {
    // per-row sumsq/absmax: lane partial over 8 cols, then 16-lane shfl, then 4-wave LDS
#pragma unroll
    for (int fm = 0; fm < 2; ++fm)
#pragma unroll
      for (int j = 0; j < 4; ++j) {
        float ss = 0.f, mx = 0.f;
#pragma unroll
        for (int fn = 0; fn < 8; ++fn) {
          float h = acc[fm][fn][j];
          ss += h * h; mx = fmaxf(mx, h);  // h >= 0 after relu
        }
#pragma unroll
        for (int m = 8; m >= 1; m >>= 1) { ss += __shfl_xor(ss, m); mx = fmaxf(mx, __shfl_xor(mx, m)); }
        if (lr == 0) {
          int rl = wm * 32 + fm * 16 + kg * 4 + j;
          u.ep.sq[rl][wn] = ss;
          u.ep.mx[rl][wn] = mx;
        }
      }
    __syncthreads();
#pragma unroll
    for (int fm = 0; fm < 2; ++fm)
#pragma unroll
      for (int j = 0; j < 4; ++j) {
        const int rl = wm * 32 + fm * 16 + kg * 4 + j;
        float sst = (u.ep.sq[rl][0] + u.ep.sq[rl][1]) + (u.ep.sq[rl][2] + u.ep.sq[rl][3]);
        float mxt = fmaxf(fmaxf(u.ep.mx[rl][0], u.ep.mx[rl][1]),
                          fmaxf(u.ep.mx[rl][2], u.ep.mx[rl][3]));
        float inv = 1.0f / sqrtf(sst * (1.0f / 512.0f) + 1e-6f);
        float amax = fmaxf(mxt * inv, 1e-5f);
        float s = 127.0f / amax;
        if (lr == 0 && wn == 0) rActOut[row0 + rl] = amax / 127.0f;
#pragma unroll
        for (int fn = 0; fn < 8; ++fn) {
          float xn = acc[fm][fn][j] * inv;
          u.ep.outT[rl][wn * 128 + fn * 16 + lr] =
              f2bf(fminf(fmaxf(rintf(xn * s), -128.0f), 127.0f));
        }
      }
    __syncthreads();
    {  // coalesced write-out of quantized tile
      const int r = tid >> 3, c0 = (tid & 7) * 64;
      const s16x8* srcl = (const s16x8*)&u.ep.outT[r][c0];
      s16x8* dstg = (s16x8*)(XqOut + (row0 + r) * 512 + c0);
#pragma unroll
      for (int i = 0; i < 8; ++i) dstg[i] = srcl[i];
    }
  } else {
    float colsum[8];
#pragma unroll
    for (int fn = 0; fn < 8; ++fn) colsum[fn] = 0.f;
#pragma unroll
    for (int fm = 0; fm < 2; ++fm)
#pragma unroll
      for (int fn = 0; fn < 8; ++fn) {
        const int col = wn * 128 + fn * 16 + lr;
#pragma unroll
        for (int j = 0; j < 4; ++j) {
          const size_t rl = row0 + wm * 32 + fm * 16 + kg * 4 + j;
          float like = 1.0f / (1.0f + expf(-acc[fm][fn][j]));
          float un = prior[rl * 512 + col] * like;
          outUn[rl * 512 + col] = un;
          colsum[fn] += un;
        }
      }
#pragma unroll
    for (int fn = 0; fn < 8; ++fn) {  // sum across kg groups (rows of this wave)
      colsum[fn] += __shfl_xor(colsum[fn], 16);
      colsum[fn] += __shfl_xor(colsum[fn], 32);
    }
    if (lane < 16) {
#pragma unroll
      for (int fn = 0; fn < 8; ++fn)
        atomicAdd(&normPart[wn * 128 + fn * 16 + lane], colsum[fn]);  // 2 adders: deterministic
    }
    __syncthreads();
    partG[(size_t)blockIdx.x * 512 + tid] = normPart[tid];
  }
}

// ---------------- normalization over S ----------------
__global__ void kNorm1(const float* __restrict__ partG, float* __restrict__ normA) {
  const int b = blockIdx.x, f = threadIdx.x;  // 32 x 512
  float s = 0.f;
#pragma unroll
  for (int i = 0; i < 16; ++i) s += partG[(size_t)(b * 16 + i) * 512 + f];
  normA[b * 512 + f] = fmaxf(s, 1e-10f);
}

__global__ void kNorm2(float* __restrict__ out, const float* __restrict__ normA) {
  const size_t i4 = (size_t)blockIdx.x * blockDim.x + threadIdx.x;  // float4 index
  f32x4 v = ((const f32x4*)out)[i4];
  const int f4 = (int)(i4 & 127);
  const int b = (int)(i4 >> 17);  // 512*1024/4 = 2^17 float4 per batch
  f32x4 n = ((const f32x4*)normA)[b * 128 + f4];
  v[0] /= n[0]; v[1] /= n[1]; v[2] /= n[2]; v[3] /= n[3];
  ((f32x4*)out)[i4] = v;
}

// ---------------- launcher ----------------
extern "C" void kernel_launch(void* const* d_in, const int* in_sizes, int n_in,
                              void* d_out, int out_size, void* d_ws, size_t ws_size,
                              hipStream_t stream) {
  const float* evid  = (const float*)d_in[0];   // [32,1024,512]
  const float* prior = (const float*)d_in[1];   // [32,1024,512]
  const float* W1    = (const float*)d_in[2];   // [512,1024]
  const float* b1    = (const float*)d_in[3];   // [512]
  const float* W2    = (const float*)d_in[4];   // [512,512]
  const float* b2    = (const float*)d_in[5];   // [512]
  float* out = (float*)d_out;

  char* ws = (char*)d_ws;
  short*  X2q   = (short*)ws;                      // 33,554,432 B
  short*  W1q   = (short*)(ws + 33554432);         //  1,048,576 B
  short*  W2q   = (short*)(ws + 34603008);         //    524,288 B
  float*  r1    = (float*)(ws + 35127296);         //    131,072 B
  float*  r2    = (float*)(ws + 35258368);         //    131,072 B
  double* p1    = (double*)(ws + 35389440);        //      2,048 B
  double* p2    = (double*)(ws + 35391488);        //      2,048 B
  float*  wsv   = (float*)(ws + 35393536);         //        256 B
  float*  partG = (float*)(ws + 35393792);         //  1,048,576 B
  float*  normA = (float*)(ws + 36442368);         //     65,536 B  (total ~36.5 MB)

  // X1q (bf16 [32768,1024] = 67,108,864 B) lives in d_out (same size); dead before GEMM2 writes.
  short* X1q = (short*)d_out;

  kWabs<<<256, 256, 0, stream>>>(W1, 524288, p1);
  kWabs<<<256, 256, 0, stream>>>(W2, 262144, p2);
  kWfin<<<2, 256, 0, stream>>>(p1, p2, wsv);
  kWq<<<2048, 256, 0, stream>>>(W1, 524288, wsv + 0, W1q);
  kWq<<<1024, 256, 0, stream>>>(W2, 262144, wsv + 1, W2q);
  kQ1<<<32768, 256, 0, stream>>>(prior, evid, X1q, r1);
  kGemm<32, true><<<512, 512, 0, stream>>>(X1q, W1q, b1, r1, wsv + 0,
                                           X2q, r2, nullptr, nullptr, nullptr);
  kGemm<16, false><<<512, 512, 0, stream>>>(X2q, W2q, b2, r2, wsv + 1,
                                            nullptr, nullptr, prior, out, partG);
  kNorm1<<<32, 512, 0, stream>>>(partG, normA);
  kNorm2<<<16384, 256, 0, stream>>>(out, normA);
}

// Round 4
// 149.673 us; speedup vs baseline: 1.4650x; 1.4650x over previous
//
#include <hip/hip_runtime.h>
#include <math.h>

typedef __attribute__((ext_vector_type(4))) int i32x4;
typedef __attribute__((ext_vector_type(4))) float f32x4;

#define GLOAD_LDS16(g, l)                                          \
  __builtin_amdgcn_global_load_lds(                                \
      (const __attribute__((address_space(1))) void*)(g),          \
      (__attribute__((address_space(3))) void*)(l), 16, 0, 0)

// ---------------- weight quantization ----------------
__global__ void kWabs(const float* __restrict__ w, int n, double* __restrict__ part) {
  int t = blockIdx.x * 256 + threadIdx.x;
  double s = 0.0;
  for (int i = t; i < n; i += 65536) s += (double)fabsf(w[i]);
#pragma unroll
  for (int m = 32; m >= 1; m >>= 1) s += __shfl_xor(s, m);
  __shared__ double sd[4];
  int lane = threadIdx.x & 63, wid = threadIdx.x >> 6;
  if (lane == 0) sd[wid] = s;
  __syncthreads();
  if (threadIdx.x == 0) part[blockIdx.x] = (sd[0] + sd[1]) + (sd[2] + sd[3]);
}

__global__ void kWfin(const double* __restrict__ p1, const double* __restrict__ p2,
                      float* __restrict__ wsv) {
  const double* p = (blockIdx.x == 0) ? p1 : p2;
  const double n = (blockIdx.x == 0) ? 524288.0 : 262144.0;
  double s = p[threadIdx.x];
#pragma unroll
  for (int m = 32; m >= 1; m >>= 1) s += __shfl_xor(s, m);
  __shared__ double sd[4];
  int lane = threadIdx.x & 63, wid = threadIdx.x >> 6;
  if (lane == 0) sd[wid] = s;
  __syncthreads();
  if (threadIdx.x == 0) {
    double tot = (sd[0] + sd[1]) + (sd[2] + sd[3]);
    wsv[blockIdx.x] = fmaxf((float)(tot / n), 1e-5f);  // = 1/scale_w
  }
}

__global__ void kWq(const float* __restrict__ w, int n, const float* __restrict__ wsv,
                    char* __restrict__ wq) {
  int i = blockIdx.x * 256 + threadIdx.x;
  if (i >= n) return;
  float scale = 1.0f / wsv[0];
  float q = fminf(fmaxf(rintf(w[i] * scale), -1.0f), 1.0f);
  wq[i] = (char)(int)q;
}

// ---------------- input RMSNorm + activation quant (concat prior||evidence) ----------------
__global__ void kQ1(const float* __restrict__ prior, const float* __restrict__ evid,
                    char* __restrict__ Xq, float* __restrict__ rAct) {
  const int row = blockIdx.x;  // token in [0, 32768)
  const int t = threadIdx.x;   // 256 threads x 4 f32
  const f32x4* src = (t < 128) ? (const f32x4*)(prior + (size_t)row * 512)
                               : (const f32x4*)(evid + (size_t)row * 512);
  f32x4 x = src[t & 127];
  float ss = 0.f, mx = 0.f;
#pragma unroll
  for (int i = 0; i < 4; ++i) { ss += x[i] * x[i]; mx = fmaxf(mx, fabsf(x[i])); }
#pragma unroll
  for (int m = 32; m >= 1; m >>= 1) { ss += __shfl_xor(ss, m); mx = fmaxf(mx, __shfl_xor(mx, m)); }
  __shared__ float sss[4], smx[4];
  const int lane = t & 63, wid = t >> 6;
  if (lane == 0) { sss[wid] = ss; smx[wid] = mx; }
  __syncthreads();
  ss = (sss[0] + sss[1]) + (sss[2] + sss[3]);
  mx = fmaxf(fmaxf(smx[0], smx[1]), fmaxf(smx[2], smx[3]));
  const float inv = 1.0f / sqrtf(ss * (1.0f / 1024.0f) + 1e-6f);
  const float amax = fmaxf(mx * inv, 1e-5f);
  const float s = 127.0f / amax;
  int pack = 0;
#pragma unroll
  for (int i = 0; i < 4; ++i) {
    float xn = x[i] * inv;
    int qi = (int)fminf(fmaxf(rintf(xn * s), -128.0f), 127.0f);
    pack |= (qi & 255) << (8 * i);
  }
  *(int*)(Xq + (size_t)row * 1024 + t * 4) = pack;
  if (t == 0) rAct[row] = amax / 127.0f;
}

// ---------------- fused BitLinear GEMM, i8 MFMA, 64 x 512 tile (full N) ----------------
// 8 waves, each owns 64 rows x 64 cols. BK=64, global_load_lds(16B) staging.
// L1: +ReLU +row-RMSNorm +requant -> i8 X2q, r2
// L2: +sigmoid, *prior -> unnormalized posterior + per-block col sums
template <int KDIM, bool L1>
__global__ __launch_bounds__(512, 4) void kGemm(
    const char* __restrict__ Xq, const char* __restrict__ Wq,
    const float* __restrict__ biasG, const float* __restrict__ rAct,
    const float* __restrict__ wS,
    char* __restrict__ XqOut, float* __restrict__ rActOut,
    const float* __restrict__ prior, float* __restrict__ outUn,
    float* __restrict__ partG) {
  __shared__ __align__(16) union {
    struct { char A[4096]; char B[32768]; } st;      // linear: global_load_lds dest
    struct { float sq[64][8]; float mx[64][8]; } ep; // L1 cross-wave row reduce
  } u;
  __shared__ float rowR[64];
  __shared__ float biasS[512];
  __shared__ float normPart[512];

  const int tid = threadIdx.x;
  const int lane = tid & 63;
  const int wn = tid >> 6;   // wave -> 64-col strip (0..7)
  const int lr = lane & 15;
  const int kg = lane >> 4;  // 0..3
  const size_t row0 = (size_t)blockIdx.x * 64;

  if (tid < 64) rowR[tid] = rAct[row0 + tid];
  biasS[tid] = biasG[tid];

  i32x4 acc[4][4];
#pragma unroll
  for (int a = 0; a < 4; ++a)
#pragma unroll
    for (int b = 0; b < 4; ++b) acc[a][b] = (i32x4){0, 0, 0, 0};

  const int lrow = lane >> 2;        // row within a 16-row chunk
  const int lkb = (lane & 3) * 16;   // 16B k-slice within a 64B row

  for (int kt = 0; kt < KDIM / 64; ++kt) {
    const int k0 = kt * 64;
    if (wn < 4) {  // A tile 64x64 i8 = 4 wave-chunks
      const char* g = Xq + (row0 + wn * 16 + lrow) * (size_t)KDIM + k0 + lkb;
      GLOAD_LDS16(g, &u.st.A[wn * 1024]);
    }
#pragma unroll
    for (int r = 0; r < 4; ++r) {  // B tile 512x64 i8 = 32 wave-chunks
      const int c = wn * 4 + r;
      const char* g = Wq + (c * 16 + lrow) * (size_t)KDIM + k0 + lkb;
      GLOAD_LDS16(g, &u.st.B[c * 1024]);
    }
    __syncthreads();  // drains vmcnt -> staged data visible
    i32x4 af[4];
#pragma unroll
    for (int fm = 0; fm < 4; ++fm)
      af[fm] = *(const i32x4*)&u.st.A[(fm * 16 + lr) * 64 + kg * 16];
#pragma unroll
    for (int fn = 0; fn < 4; ++fn) {
      i32x4 bf = *(const i32x4*)&u.st.B[(wn * 64 + fn * 16 + lr) * 64 + kg * 16];
#pragma unroll
      for (int fm = 0; fm < 4; ++fm)
        acc[fm][fn] = __builtin_amdgcn_mfma_i32_16x16x64_i8(af[fm], bf, acc[fm][fn], 0, 0, 0);
    }
    __syncthreads();  // protect LDS overwrite next step
  }

  // ---- epilogue: acc element j -> row fm*16+kg*4+j, col wn*64+fn*16+lr
  const float wsv_ = wS[0];

  if constexpr (L1) {
    f32x4 fa[4][4];
#pragma unroll
    for (int fm = 0; fm < 4; ++fm) {
      float sc[4];
#pragma unroll
      for (int j = 0; j < 4; ++j) sc[j] = rowR[fm * 16 + kg * 4 + j] * wsv_;
#pragma unroll
      for (int fn = 0; fn < 4; ++fn) {
        const float bb = biasS[wn * 64 + fn * 16 + lr];
#pragma unroll
        for (int j = 0; j < 4; ++j)
          fa[fm][fn][j] = fmaxf((float)acc[fm][fn][j] * sc[j] + bb, 0.0f);
      }
    }
    // per-row sumsq/absmax: 4 local cols -> 16-lane shfl -> cross-wave LDS
#pragma unroll
    for (int fm = 0; fm < 4; ++fm)
#pragma unroll
      for (int j = 0; j < 4; ++j) {
        float ss = 0.f, mx = 0.f;
#pragma unroll
        for (int fn = 0; fn < 4; ++fn) { float h = fa[fm][fn][j]; ss += h * h; mx = fmaxf(mx, h); }
#pragma unroll
        for (int m = 8; m >= 1; m >>= 1) { ss += __shfl_xor(ss, m); mx = fmaxf(mx, __shfl_xor(mx, m)); }
        if (lr == 0) {
          int rl = fm * 16 + kg * 4 + j;
          u.ep.sq[rl][wn] = ss;
          u.ep.mx[rl][wn] = mx;
        }
      }
    __syncthreads();
#pragma unroll
    for (int fm = 0; fm < 4; ++fm)
#pragma unroll
      for (int j = 0; j < 4; ++j) {
        const int rl = fm * 16 + kg * 4 + j;
        float sst = 0.f, mxt = 0.f;
#pragma unroll
        for (int w = 0; w < 8; ++w) {
          sst += u.ep.sq[rl][w];
          mxt = fmaxf(mxt, u.ep.mx[rl][w]);
        }
        float inv = 1.0f / sqrtf(sst * (1.0f / 512.0f) + 1e-6f);
        float amax = fmaxf(mxt * inv, 1e-5f);
        float s = 127.0f / amax;
        if (lr == 0 && wn == 0) rActOut[row0 + rl] = amax / 127.0f;
#pragma unroll
        for (int fn = 0; fn < 4; ++fn) {
          float xn = fa[fm][fn][j] * inv;
          int qi = (int)fminf(fmaxf(rintf(xn * s), -128.0f), 127.0f);
          XqOut[(row0 + rl) * 512 + wn * 64 + fn * 16 + lr] = (char)qi;
        }
      }
  } else {
    float colsum[4] = {0.f, 0.f, 0.f, 0.f};
#pragma unroll
    for (int fm = 0; fm < 4; ++fm) {
      float sc[4];
#pragma unroll
      for (int j = 0; j < 4; ++j) sc[j] = rowR[fm * 16 + kg * 4 + j] * wsv_;
#pragma unroll
      for (int fn = 0; fn < 4; ++fn) {
        const int col = wn * 64 + fn * 16 + lr;
        const float bb = biasS[col];
#pragma unroll
        for (int j = 0; j < 4; ++j) {
          const size_t rg = row0 + fm * 16 + kg * 4 + j;
          float v = (float)acc[fm][fn][j] * sc[j] + bb;
          float like = 1.0f / (1.0f + expf(-v));
          float un = prior[rg * 512 + col] * like;
          outUn[rg * 512 + col] = un;
          colsum[fn] += un;
        }
      }
    }
#pragma unroll
    for (int fn = 0; fn < 4; ++fn) {  // reduce over the wave's 4 kg row-groups
      colsum[fn] += __shfl_xor(colsum[fn], 16);
      colsum[fn] += __shfl_xor(colsum[fn], 32);
    }
    if (lane < 16) {  // one wave per column: plain store, deterministic
#pragma unroll
      for (int fn = 0; fn < 4; ++fn) normPart[wn * 64 + fn * 16 + lane] = colsum[fn];
    }
    __syncthreads();
    partG[(size_t)blockIdx.x * 512 + tid] = normPart[tid];
  }
}

// ---------------- normalization over S ----------------
__global__ void kNorm1(const float* __restrict__ partG, float* __restrict__ normA) {
  const int b = blockIdx.x, f = threadIdx.x;  // 32 x 512; 16 GEMM2 blocks per batch
  float s = 0.f;
#pragma unroll
  for (int i = 0; i < 16; ++i) s += partG[(size_t)(b * 16 + i) * 512 + f];
  normA[b * 512 + f] = fmaxf(s, 1e-10f);
}

__global__ void kNorm2(float* __restrict__ out, const float* __restrict__ normA) {
  const size_t i4 = (size_t)blockIdx.x * blockDim.x + threadIdx.x;  // float4 index
  f32x4 v = ((const f32x4*)out)[i4];
  const int f4 = (int)(i4 & 127);
  const int b = (int)(i4 >> 17);
  f32x4 n = ((const f32x4*)normA)[b * 128 + f4];
  v[0] /= n[0]; v[1] /= n[1]; v[2] /= n[2]; v[3] /= n[3];
  ((f32x4*)out)[i4] = v;
}

// ---------------- launcher ----------------
extern "C" void kernel_launch(void* const* d_in, const int* in_sizes, int n_in,
                              void* d_out, int out_size, void* d_ws, size_t ws_size,
                              hipStream_t stream) {
  const float* evid  = (const float*)d_in[0];   // [32,1024,512]
  const float* prior = (const float*)d_in[1];   // [32,1024,512]
  const float* W1    = (const float*)d_in[2];   // [512,1024]
  const float* b1    = (const float*)d_in[3];   // [512]
  const float* W2    = (const float*)d_in[4];   // [512,512]
  const float* b2    = (const float*)d_in[5];   // [512]
  float* out = (float*)d_out;

  char* ws = (char*)d_ws;
  char*   X2q   = ws;                              // 16,777,216 B (i8 [32768][512])
  char*   W1q   = ws + 16777216;                   //    524,288 B
  char*   W2q   = ws + 17301504;                   //    262,144 B
  float*  r1    = (float*)(ws + 17563648);         //    131,072 B
  float*  r2    = (float*)(ws + 17694720);         //    131,072 B
  double* p1    = (double*)(ws + 17825792);        //      2,048 B
  double* p2    = (double*)(ws + 17827840);        //      2,048 B
  float*  wsv   = (float*)(ws + 17829888);         //        256 B
  float*  partG = (float*)(ws + 17830144);         //  1,048,576 B
  float*  normA = (float*)(ws + 18878720);         //     65,536 B (total ~18.9 MB)

  // X1q (i8 [32768][1024] = 33.5 MB) lives in d_out (67 MB); dead before GEMM2 writes.
  char* X1q = (char*)d_out;

  kWabs<<<256, 256, 0, stream>>>(W1, 524288, p1);
  kWabs<<<256, 256, 0, stream>>>(W2, 262144, p2);
  kWfin<<<2, 256, 0, stream>>>(p1, p2, wsv);
  kWq<<<2048, 256, 0, stream>>>(W1, 524288, wsv + 0, W1q);
  kWq<<<1024, 256, 0, stream>>>(W2, 262144, wsv + 1, W2q);
  kQ1<<<32768, 256, 0, stream>>>(prior, evid, X1q, r1);
  kGemm<1024, true><<<512, 512, 0, stream>>>(X1q, W1q, b1, r1, wsv + 0,
                                             X2q, r2, nullptr, nullptr, nullptr);
  kGemm<512, false><<<512, 512, 0, stream>>>(X2q, W2q, b2, r2, wsv + 1,
                                             nullptr, nullptr, prior, out, partG);
  kNorm1<<<32, 512, 0, stream>>>(partG, normA);
  kNorm2<<<16384, 256, 0, stream>>>(out, normA);
}

// Round 5
// 140.071 us; speedup vs baseline: 1.5655x; 1.0685x over previous
//
#include <hip/hip_runtime.h>
#include <math.h>

typedef __attribute__((ext_vector_type(4))) int i32x4;
typedef __attribute__((ext_vector_type(4))) float f32x4;

#define GLOAD_LDS16(g, l)                                          \
  __builtin_amdgcn_global_load_lds(                                \
      (const __attribute__((address_space(1))) void*)(g),          \
      (__attribute__((address_space(3))) void*)(l), 16, 0, 0)

// ---------------- weight quantization ----------------
__global__ void kWabs(const float* __restrict__ w, int n, double* __restrict__ part) {
  int t = blockIdx.x * 256 + threadIdx.x;
  double s = 0.0;
  for (int i = t; i < n; i += 65536) s += (double)fabsf(w[i]);
#pragma unroll
  for (int m = 32; m >= 1; m >>= 1) s += __shfl_xor(s, m);
  __shared__ double sd[4];
  int lane = threadIdx.x & 63, wid = threadIdx.x >> 6;
  if (lane == 0) sd[wid] = s;
  __syncthreads();
  if (threadIdx.x == 0) part[blockIdx.x] = (sd[0] + sd[1]) + (sd[2] + sd[3]);
}

__global__ void kWfin(const double* __restrict__ p1, const double* __restrict__ p2,
                      float* __restrict__ wsv) {
  const double* p = (blockIdx.x == 0) ? p1 : p2;
  const double n = (blockIdx.x == 0) ? 524288.0 : 262144.0;
  double s = p[threadIdx.x];
#pragma unroll
  for (int m = 32; m >= 1; m >>= 1) s += __shfl_xor(s, m);
  __shared__ double sd[4];
  int lane = threadIdx.x & 63, wid = threadIdx.x >> 6;
  if (lane == 0) sd[wid] = s;
  __syncthreads();
  if (threadIdx.x == 0) {
    double tot = (sd[0] + sd[1]) + (sd[2] + sd[3]);
    wsv[blockIdx.x] = fmaxf((float)(tot / n), 1e-5f);  // = 1/scale_w
  }
}

__global__ void kWq(const float* __restrict__ w, int n, const float* __restrict__ wsv,
                    char* __restrict__ wq) {
  int i = blockIdx.x * 256 + threadIdx.x;
  if (i >= n) return;
  float scale = 1.0f / wsv[0];
  float q = fminf(fmaxf(rintf(w[i] * scale), -1.0f), 1.0f);
  wq[i] = (char)(int)q;
}

// ---------------- input RMSNorm + activation quant (concat prior||evidence) ----------------
__global__ void kQ1(const float* __restrict__ prior, const float* __restrict__ evid,
                    char* __restrict__ Xq, float* __restrict__ rAct) {
  const int row = blockIdx.x;  // token in [0, 32768)
  const int t = threadIdx.x;   // 256 threads x 4 f32
  const f32x4* src = (t < 128) ? (const f32x4*)(prior + (size_t)row * 512)
                               : (const f32x4*)(evid + (size_t)row * 512);
  f32x4 x = src[t & 127];
  float ss = 0.f, mx = 0.f;
#pragma unroll
  for (int i = 0; i < 4; ++i) { ss += x[i] * x[i]; mx = fmaxf(mx, fabsf(x[i])); }
#pragma unroll
  for (int m = 32; m >= 1; m >>= 1) { ss += __shfl_xor(ss, m); mx = fmaxf(mx, __shfl_xor(mx, m)); }
  __shared__ float sss[4], smx[4];
  const int lane = t & 63, wid = t >> 6;
  if (lane == 0) { sss[wid] = ss; smx[wid] = mx; }
  __syncthreads();
  ss = (sss[0] + sss[1]) + (sss[2] + sss[3]);
  mx = fmaxf(fmaxf(smx[0], smx[1]), fmaxf(smx[2], smx[3]));
  const float inv = 1.0f / sqrtf(ss * (1.0f / 1024.0f) + 1e-6f);
  const float amax = fmaxf(mx * inv, 1e-5f);
  const float s = 127.0f / amax;
  int pack = 0;
#pragma unroll
  for (int i = 0; i < 4; ++i) {
    float xn = x[i] * inv;
    int qi = (int)fminf(fmaxf(rintf(xn * s), -128.0f), 127.0f);
    pack |= (qi & 255) << (8 * i);
  }
  *(int*)(Xq + (size_t)row * 1024 + t * 4) = pack;
  if (t == 0) rAct[row] = amax / 127.0f;
}

// ---------------- fused BitLinear GEMM, i8 MFMA, 64 x 512 tile (full N) ----------------
// Double-buffered 2-phase: STAGE(next) issued BEFORE ds_read+MFMA(cur);
// one __syncthreads per K-step (implicit vmcnt(0) drain after MFMA cover).
// L1: +ReLU +row-RMSNorm +requant -> i8 X2q, r2
// L2: +sigmoid, *prior -> unnormalized posterior + per-block col sums
template <int KDIM, bool L1>
__global__ __launch_bounds__(512, 4) void kGemm(
    const char* __restrict__ Xq, const char* __restrict__ Wq,
    const float* __restrict__ biasG, const float* __restrict__ rAct,
    const float* __restrict__ wS,
    char* __restrict__ XqOut, float* __restrict__ rActOut,
    const float* __restrict__ prior, float* __restrict__ outUn,
    float* __restrict__ partG) {
  struct Stage { char A[4096]; char B[32768]; };
  __shared__ __align__(16) union {
    Stage st[2];                                     // 73,728 B double buffer
    struct { float sq[64][8]; float mx[64][8]; } ep; // L1 cross-wave row reduce (overlays st[0])
  } u;
  __shared__ float rowR[64];
  __shared__ float biasS[512];
  __shared__ float normPart[512];

  const int tid = threadIdx.x;
  const int lane = tid & 63;
  const int wn = tid >> 6;   // wave -> 64-col strip (0..7)
  const int lr = lane & 15;
  const int kg = lane >> 4;  // 0..3
  const size_t row0 = (size_t)blockIdx.x * 64;

  if (tid < 64) rowR[tid] = rAct[row0 + tid];
  biasS[tid] = biasG[tid];

  i32x4 acc[4][4];
#pragma unroll
  for (int a = 0; a < 4; ++a)
#pragma unroll
    for (int b = 0; b < 4; ++b) acc[a][b] = (i32x4){0, 0, 0, 0};

  const int lrow = lane >> 2;       // row within a 16-row chunk
  const int lkb = (lane & 3) * 16;  // 16B k-slice within a 64B row

  // wave-invariant global bases (advance by k0 per step)
  const char* gA = Xq + (row0 + (wn & 3) * 16 + lrow) * (size_t)KDIM + lkb;
  const char* gB[4];
#pragma unroll
  for (int r = 0; r < 4; ++r)
    gB[r] = Wq + ((wn * 4 + r) * 16 + lrow) * (size_t)KDIM + lkb;

#define STAGE(b, k0)                                                   \
  do {                                                                 \
    if (wn < 4) GLOAD_LDS16(gA + (k0), &u.st[b].A[(wn & 3) * 1024]);   \
    _Pragma("unroll")                                                  \
    for (int r = 0; r < 4; ++r)                                        \
      GLOAD_LDS16(gB[r] + (k0), &u.st[b].B[(wn * 4 + r) * 1024]);      \
  } while (0)

  constexpr int NT = KDIM / 64;
  STAGE(0, 0);
  __syncthreads();  // vmcnt(0) drain: buf0 ready

#pragma unroll 2
  for (int kt = 0; kt < NT; ++kt) {
    const int cur = kt & 1;
    if (kt + 1 < NT) STAGE(cur ^ 1, (kt + 1) * 64);  // prefetch BEFORE compute
    i32x4 af[4];
#pragma unroll
    for (int fm = 0; fm < 4; ++fm)
      af[fm] = *(const i32x4*)&u.st[cur].A[(fm * 16 + lr) * 64 + kg * 16];
#pragma unroll
    for (int fn = 0; fn < 4; ++fn) {
      i32x4 bf = *(const i32x4*)&u.st[cur].B[(wn * 64 + fn * 16 + lr) * 64 + kg * 16];
#pragma unroll
      for (int fm = 0; fm < 4; ++fm)
        acc[fm][fn] = __builtin_amdgcn_mfma_i32_16x16x64_i8(af[fm], bf, acc[fm][fn], 0, 0, 0);
    }
    __syncthreads();  // drains vmcnt(0): prefetched buf ready; cur safe to overwrite
  }
#undef STAGE

  // ---- epilogue: acc element j -> row fm*16+kg*4+j, col wn*64+fn*16+lr
  const float wsv_ = wS[0];

  if constexpr (L1) {
    f32x4 fa[4][4];
#pragma unroll
    for (int fm = 0; fm < 4; ++fm) {
      float sc[4];
#pragma unroll
      for (int j = 0; j < 4; ++j) sc[j] = rowR[fm * 16 + kg * 4 + j] * wsv_;
#pragma unroll
      for (int fn = 0; fn < 4; ++fn) {
        const float bb = biasS[wn * 64 + fn * 16 + lr];
#pragma unroll
        for (int j = 0; j < 4; ++j)
          fa[fm][fn][j] = fmaxf((float)acc[fm][fn][j] * sc[j] + bb, 0.0f);
      }
    }
    // per-row sumsq/absmax: 4 local cols -> 16-lane shfl -> cross-wave LDS
#pragma unroll
    for (int fm = 0; fm < 4; ++fm)
#pragma unroll
      for (int j = 0; j < 4; ++j) {
        float ss = 0.f, mx = 0.f;
#pragma unroll
        for (int fn = 0; fn < 4; ++fn) { float h = fa[fm][fn][j]; ss += h * h; mx = fmaxf(mx, h); }
#pragma unroll
        for (int m = 8; m >= 1; m >>= 1) { ss += __shfl_xor(ss, m); mx = fmaxf(mx, __shfl_xor(mx, m)); }
        if (lr == 0) {
          int rl = fm * 16 + kg * 4 + j;
          u.ep.sq[rl][wn] = ss;
          u.ep.mx[rl][wn] = mx;
        }
      }
    __syncthreads();
#pragma unroll
    for (int fm = 0; fm < 4; ++fm)
#pragma unroll
      for (int j = 0; j < 4; ++j) {
        const int rl = fm * 16 + kg * 4 + j;
        float sst = 0.f, mxt = 0.f;
#pragma unroll
        for (int w = 0; w < 8; ++w) {
          sst += u.ep.sq[rl][w];
          mxt = fmaxf(mxt, u.ep.mx[rl][w]);
        }
        float inv = 1.0f / sqrtf(sst * (1.0f / 512.0f) + 1e-6f);
        float amax = fmaxf(mxt * inv, 1e-5f);
        float s = 127.0f / amax;
        if (lr == 0 && wn == 0) rActOut[row0 + rl] = amax / 127.0f;
#pragma unroll
        for (int fn = 0; fn < 4; ++fn) {
          float xn = fa[fm][fn][j] * inv;
          int qi = (int)fminf(fmaxf(rintf(xn * s), -128.0f), 127.0f);
          XqOut[(row0 + rl) * 512 + wn * 64 + fn * 16 + lr] = (char)qi;
        }
      }
  } else {
    float colsum[4] = {0.f, 0.f, 0.f, 0.f};
#pragma unroll
    for (int fm = 0; fm < 4; ++fm) {
      float sc[4];
#pragma unroll
      for (int j = 0; j < 4; ++j) sc[j] = rowR[fm * 16 + kg * 4 + j] * wsv_;
#pragma unroll
      for (int fn = 0; fn < 4; ++fn) {
        const int col = wn * 64 + fn * 16 + lr;
        const float bb = biasS[col];
#pragma unroll
        for (int j = 0; j < 4; ++j) {
          const size_t rg = row0 + fm * 16 + kg * 4 + j;
          float v = (float)acc[fm][fn][j] * sc[j] + bb;
          float like = 1.0f / (1.0f + expf(-v));
          float un = prior[rg * 512 + col] * like;
          outUn[rg * 512 + col] = un;
          colsum[fn] += un;
        }
      }
    }
#pragma unroll
    for (int fn = 0; fn < 4; ++fn) {  // reduce over the wave's 4 kg row-groups
      colsum[fn] += __shfl_xor(colsum[fn], 16);
      colsum[fn] += __shfl_xor(colsum[fn], 32);
    }
    if (lane < 16) {  // one wave per column strip: plain store, deterministic
#pragma unroll
      for (int fn = 0; fn < 4; ++fn) normPart[wn * 64 + fn * 16 + lane] = colsum[fn];
    }
    __syncthreads();
    partG[(size_t)blockIdx.x * 512 + tid] = normPart[tid];
  }
}

// ---------------- normalization over S ----------------
__global__ void kNorm1(const float* __restrict__ partG, float* __restrict__ normA) {
  const int b = blockIdx.x, f = threadIdx.x;  // 32 x 512; 16 GEMM2 blocks per batch
  float s = 0.f;
#pragma unroll
  for (int i = 0; i < 16; ++i) s += partG[(size_t)(b * 16 + i) * 512 + f];
  normA[b * 512 + f] = fmaxf(s, 1e-10f);
}

__global__ void kNorm2(float* __restrict__ out, const float* __restrict__ normA) {
  const size_t i4 = (size_t)blockIdx.x * blockDim.x + threadIdx.x;  // float4 index
  f32x4 v = ((const f32x4*)out)[i4];
  const int f4 = (int)(i4 & 127);
  const int b = (int)(i4 >> 17);
  f32x4 n = ((const f32x4*)normA)[b * 128 + f4];
  v[0] /= n[0]; v[1] /= n[1]; v[2] /= n[2]; v[3] /= n[3];
  ((f32x4*)out)[i4] = v;
}

// ---------------- launcher ----------------
extern "C" void kernel_launch(void* const* d_in, const int* in_sizes, int n_in,
                              void* d_out, int out_size, void* d_ws, size_t ws_size,
                              hipStream_t stream) {
  const float* evid  = (const float*)d_in[0];   // [32,1024,512]
  const float* prior = (const float*)d_in[1];   // [32,1024,512]
  const float* W1    = (const float*)d_in[2];   // [512,1024]
  const float* b1    = (const float*)d_in[3];   // [512]
  const float* W2    = (const float*)d_in[4];   // [512,512]
  const float* b2    = (const float*)d_in[5];   // [512]
  float* out = (float*)d_out;

  char* ws = (char*)d_ws;
  char*   X2q   = ws;                              // 16,777,216 B (i8 [32768][512])
  char*   W1q   = ws + 16777216;                   //    524,288 B
  char*   W2q   = ws + 17301504;                   //    262,144 B
  float*  r1    = (float*)(ws + 17563648);         //    131,072 B
  float*  r2    = (float*)(ws + 17694720);         //    131,072 B
  double* p1    = (double*)(ws + 17825792);        //      2,048 B
  double* p2    = (double*)(ws + 17827840);        //      2,048 B
  float*  wsv   = (float*)(ws + 17829888);         //        256 B
  float*  partG = (float*)(ws + 17830144);         //  1,048,576 B
  float*  normA = (float*)(ws + 18878720);         //     65,536 B (total ~18.9 MB)

  // X1q (i8 [32768][1024] = 33.5 MB) lives in d_out (67 MB); dead before GEMM2 writes.
  char* X1q = (char*)d_out;

  kWabs<<<256, 256, 0, stream>>>(W1, 524288, p1);
  kWabs<<<256, 256, 0, stream>>>(W2, 262144, p2);
  kWfin<<<2, 256, 0, stream>>>(p1, p2, wsv);
  kWq<<<2048, 256, 0, stream>>>(W1, 524288, wsv + 0, W1q);
  kWq<<<1024, 256, 0, stream>>>(W2, 262144, wsv + 1, W2q);
  kQ1<<<32768, 256, 0, stream>>>(prior, evid, X1q, r1);
  kGemm<1024, true><<<512, 512, 0, stream>>>(X1q, W1q, b1, r1, wsv + 0,
                                             X2q, r2, nullptr, nullptr, nullptr);
  kGemm<512, false><<<512, 512, 0, stream>>>(X2q, W2q, b2, r2, wsv + 1,
                                             nullptr, nullptr, prior, out, partG);
  kNorm1<<<32, 512, 0, stream>>>(partG, normA);
  kNorm2<<<16384, 256, 0, stream>>>(out, normA);
}

// Round 6
// 131.783 us; speedup vs baseline: 1.6639x; 1.0629x over previous
//
#include <hip/hip_runtime.h>
#include <math.h>

typedef __attribute__((ext_vector_type(4))) int i32x4;
typedef __attribute__((ext_vector_type(2))) int i32x2;
typedef __attribute__((ext_vector_type(4))) float f32x4;

#define GLOAD_LDS16(g, l)                                          \
  __builtin_amdgcn_global_load_lds(                                \
      (const __attribute__((address_space(1))) void*)(g),          \
      (__attribute__((address_space(3))) void*)(l), 16, 0, 0)

// ---------------- weight quantization (merged: W1 blocks 0-255, W2 blocks 256-511) ----------
__global__ void kWabs(const float* __restrict__ w1, const float* __restrict__ w2,
                      double* __restrict__ part) {
  const bool second = blockIdx.x >= 256;
  const float* w = second ? w2 : w1;
  const int n = second ? 262144 : 524288;
  int t = (blockIdx.x & 255) * 256 + threadIdx.x;
  double s = 0.0;
  for (int i = t; i < n; i += 65536) s += (double)fabsf(w[i]);
#pragma unroll
  for (int m = 32; m >= 1; m >>= 1) s += __shfl_xor(s, m);
  __shared__ double sd[4];
  int lane = threadIdx.x & 63, wid = threadIdx.x >> 6;
  if (lane == 0) sd[wid] = s;
  __syncthreads();
  if (threadIdx.x == 0) part[blockIdx.x] = (sd[0] + sd[1]) + (sd[2] + sd[3]);
}

__global__ void kWfin(const double* __restrict__ part, float* __restrict__ wsv) {
  const double* p = part + blockIdx.x * 256;
  const double n = (blockIdx.x == 0) ? 524288.0 : 262144.0;
  double s = p[threadIdx.x];
#pragma unroll
  for (int m = 32; m >= 1; m >>= 1) s += __shfl_xor(s, m);
  __shared__ double sd[4];
  int lane = threadIdx.x & 63, wid = threadIdx.x >> 6;
  if (lane == 0) sd[wid] = s;
  __syncthreads();
  if (threadIdx.x == 0) {
    double tot = (sd[0] + sd[1]) + (sd[2] + sd[3]);
    wsv[blockIdx.x] = fmaxf((float)(tot / n), 1e-5f);  // = 1/scale_w
  }
}

__global__ void kWq(const float* __restrict__ w1, const float* __restrict__ w2,
                    const float* __restrict__ wsv,
                    char* __restrict__ wq1, char* __restrict__ wq2) {
  const bool second = blockIdx.x >= 2048;
  const float* w = second ? w2 : w1;
  char* wq = second ? wq2 : wq1;
  const float scale = 1.0f / wsv[second ? 1 : 0];
  int i = (second ? blockIdx.x - 2048 : blockIdx.x) * 256 + threadIdx.x;
  float q = fminf(fmaxf(rintf(w[i] * scale), -1.0f), 1.0f);
  wq[i] = (char)(int)q;
}

// ---------------- input RMSNorm + absmax quant: wave-per-row, barrier-free ----------------
__global__ __launch_bounds__(512) void kQ1(
    const float* __restrict__ prior, const float* __restrict__ evid,
    char* __restrict__ Xq, float* __restrict__ rAct) {
  const int w = threadIdx.x >> 6;
  const int l = threadIdx.x & 63;
  const size_t row = (size_t)blockIdx.x * 8 + w;
  const f32x4* pp = (const f32x4*)(prior + row * 512) + l * 2;
  const f32x4* pe = (const f32x4*)(evid + row * 512) + l * 2;
  f32x4 x[4];
  x[0] = pp[0]; x[1] = pp[1]; x[2] = pe[0]; x[3] = pe[1];
  float ss = 0.f, mx = 0.f;
#pragma unroll
  for (int v = 0; v < 4; ++v)
#pragma unroll
    for (int i = 0; i < 4; ++i) { float f = x[v][i]; ss += f * f; mx = fmaxf(mx, fabsf(f)); }
#pragma unroll
  for (int m = 32; m >= 1; m >>= 1) { ss += __shfl_xor(ss, m); mx = fmaxf(mx, __shfl_xor(mx, m)); }
  const float inv = 1.0f / sqrtf(ss * (1.0f / 1024.0f) + 1e-6f);
  const float amax = fmaxf(mx * inv, 1e-5f);
  const float s = 127.0f / amax;
  int pk[4];
#pragma unroll
  for (int v = 0; v < 4; ++v) {
    int p = 0;
#pragma unroll
    for (int i = 0; i < 4; ++i) {
      int qi = (int)fminf(fmaxf(rintf(x[v][i] * inv * s), -128.0f), 127.0f);
      p |= (qi & 255) << (8 * i);
    }
    pk[v] = p;
  }
  char* dst = Xq + row * 1024 + l * 8;
  *(i32x2*)dst = (i32x2){pk[0], pk[1]};          // prior half: k = l*8 .. l*8+7
  *(i32x2*)(dst + 512) = (i32x2){pk[2], pk[3]};  // evid half:  k = 512 + l*8 ..
  if (l == 0) rAct[row] = amax / 127.0f;
}

// ---------------- fused BitLinear GEMM, i8 MFMA, 64 x 512 tile (full N) ----------------
// Double-buffered 2-phase: STAGE(next) issued BEFORE ds_read+MFMA(cur);
// one __syncthreads per K-step (implicit vmcnt(0) drain after MFMA cover).
// L1: +ReLU +row-RMSNorm +requant -> i8 X2q, r2
// L2: +sigmoid, *prior -> unnormalized posterior + per-block col sums
template <int KDIM, bool L1>
__global__ __launch_bounds__(512, 4) void kGemm(
    const char* __restrict__ Xq, const char* __restrict__ Wq,
    const float* __restrict__ biasG, const float* __restrict__ rAct,
    const float* __restrict__ wS,
    char* __restrict__ XqOut, float* __restrict__ rActOut,
    const float* __restrict__ prior, float* __restrict__ outUn,
    float* __restrict__ partG) {
  struct Stage { char A[4096]; char B[32768]; };
  __shared__ __align__(16) union {
    Stage st[2];                                     // 73,728 B double buffer
    struct { float sq[64][8]; float mx[64][8]; } ep; // L1 cross-wave row reduce (overlays st[0])
  } u;
  __shared__ float rowR[64];
  __shared__ float biasS[512];
  __shared__ float normPart[512];

  const int tid = threadIdx.x;
  const int lane = tid & 63;
  const int wn = tid >> 6;   // wave -> 64-col strip (0..7)
  const int lr = lane & 15;
  const int kg = lane >> 4;  // 0..3
  const size_t row0 = (size_t)blockIdx.x * 64;

  if (tid < 64) rowR[tid] = rAct[row0 + tid];
  biasS[tid] = biasG[tid];

  i32x4 acc[4][4];
#pragma unroll
  for (int a = 0; a < 4; ++a)
#pragma unroll
    for (int b = 0; b < 4; ++b) acc[a][b] = (i32x4){0, 0, 0, 0};

  const int lrow = lane >> 2;       // row within a 16-row chunk
  const int lkb = (lane & 3) * 16;  // 16B k-slice within a 64B row

  // wave-invariant global bases (advance by k0 per step)
  const char* gA = Xq + (row0 + (wn & 3) * 16 + lrow) * (size_t)KDIM + lkb;
  const char* gB[4];
#pragma unroll
  for (int r = 0; r < 4; ++r)
    gB[r] = Wq + ((wn * 4 + r) * 16 + lrow) * (size_t)KDIM + lkb;

#define STAGE(b, k0)                                                   \
  do {                                                                 \
    if (wn < 4) GLOAD_LDS16(gA + (k0), &u.st[b].A[(wn & 3) * 1024]);   \
    _Pragma("unroll")                                                  \
    for (int r = 0; r < 4; ++r)                                        \
      GLOAD_LDS16(gB[r] + (k0), &u.st[b].B[(wn * 4 + r) * 1024]);      \
  } while (0)

  constexpr int NT = KDIM / 64;
  STAGE(0, 0);
  __syncthreads();  // vmcnt(0) drain: buf0 ready

#pragma unroll 2
  for (int kt = 0; kt < NT; ++kt) {
    const int cur = kt & 1;
    if (kt + 1 < NT) STAGE(cur ^ 1, (kt + 1) * 64);  // prefetch BEFORE compute
    i32x4 af[4];
#pragma unroll
    for (int fm = 0; fm < 4; ++fm)
      af[fm] = *(const i32x4*)&u.st[cur].A[(fm * 16 + lr) * 64 + kg * 16];
#pragma unroll
    for (int fn = 0; fn < 4; ++fn) {
      i32x4 bf = *(const i32x4*)&u.st[cur].B[(wn * 64 + fn * 16 + lr) * 64 + kg * 16];
#pragma unroll
      for (int fm = 0; fm < 4; ++fm)
        acc[fm][fn] = __builtin_amdgcn_mfma_i32_16x16x64_i8(af[fm], bf, acc[fm][fn], 0, 0, 0);
    }
    __syncthreads();  // drains vmcnt(0): prefetched buf ready; cur safe to overwrite
  }
#undef STAGE

  // ---- epilogue: acc element j -> row fm*16+kg*4+j, col wn*64+fn*16+lr
  const float wsv_ = wS[0];

  if constexpr (L1) {
    f32x4 fa[4][4];
#pragma unroll
    for (int fm = 0; fm < 4; ++fm) {
      float sc[4];
#pragma unroll
      for (int j = 0; j < 4; ++j) sc[j] = rowR[fm * 16 + kg * 4 + j] * wsv_;
#pragma unroll
      for (int fn = 0; fn < 4; ++fn) {
        const float bb = biasS[wn * 64 + fn * 16 + lr];
#pragma unroll
        for (int j = 0; j < 4; ++j)
          fa[fm][fn][j] = fmaxf((float)acc[fm][fn][j] * sc[j] + bb, 0.0f);
      }
    }
    // per-row sumsq/absmax: 4 local cols -> 16-lane shfl -> cross-wave LDS
#pragma unroll
    for (int fm = 0; fm < 4; ++fm)
#pragma unroll
      for (int j = 0; j < 4; ++j) {
        float ss = 0.f, mx = 0.f;
#pragma unroll
        for (int fn = 0; fn < 4; ++fn) { float h = fa[fm][fn][j]; ss += h * h; mx = fmaxf(mx, h); }
#pragma unroll
        for (int m = 8; m >= 1; m >>= 1) { ss += __shfl_xor(ss, m); mx = fmaxf(mx, __shfl_xor(mx, m)); }
        if (lr == 0) {
          int rl = fm * 16 + kg * 4 + j;
          u.ep.sq[rl][wn] = ss;
          u.ep.mx[rl][wn] = mx;
        }
      }
    __syncthreads();
#pragma unroll
    for (int fm = 0; fm < 4; ++fm)
#pragma unroll
      for (int j = 0; j < 4; ++j) {
        const int rl = fm * 16 + kg * 4 + j;
        float sst = 0.f, mxt = 0.f;
#pragma unroll
        for (int w = 0; w < 8; ++w) {
          sst += u.ep.sq[rl][w];
          mxt = fmaxf(mxt, u.ep.mx[rl][w]);
        }
        float inv = 1.0f / sqrtf(sst * (1.0f / 512.0f) + 1e-6f);
        float amax = fmaxf(mxt * inv, 1e-5f);
        float s = 127.0f / amax;
        if (lr == 0 && wn == 0) rActOut[row0 + rl] = amax / 127.0f;
#pragma unroll
        for (int fn = 0; fn < 4; ++fn) {
          float xn = fa[fm][fn][j] * inv;
          int qi = (int)fminf(fmaxf(rintf(xn * s), -128.0f), 127.0f);
          XqOut[(row0 + rl) * 512 + wn * 64 + fn * 16 + lr] = (char)qi;
        }
      }
  } else {
    float colsum[4] = {0.f, 0.f, 0.f, 0.f};
#pragma unroll
    for (int fm = 0; fm < 4; ++fm) {
      float sc[4];
#pragma unroll
      for (int j = 0; j < 4; ++j) sc[j] = rowR[fm * 16 + kg * 4 + j] * wsv_;
#pragma unroll
      for (int fn = 0; fn < 4; ++fn) {
        const int col = wn * 64 + fn * 16 + lr;
        const float bb = biasS[col];
#pragma unroll
        for (int j = 0; j < 4; ++j) {
          const size_t rg = row0 + fm * 16 + kg * 4 + j;
          float v = (float)acc[fm][fn][j] * sc[j] + bb;
          float like = 1.0f / (1.0f + expf(-v));
          float un = prior[rg * 512 + col] * like;
          outUn[rg * 512 + col] = un;
          colsum[fn] += un;
        }
      }
    }
#pragma unroll
    for (int fn = 0; fn < 4; ++fn) {  // reduce over the wave's 4 kg row-groups
      colsum[fn] += __shfl_xor(colsum[fn], 16);
      colsum[fn] += __shfl_xor(colsum[fn], 32);
    }
    if (lane < 16) {  // one wave per column strip: plain store, deterministic
#pragma unroll
      for (int fn = 0; fn < 4; ++fn) normPart[wn * 64 + fn * 16 + lane] = colsum[fn];
    }
    __syncthreads();
    partG[(size_t)blockIdx.x * 512 + tid] = normPart[tid];
  }
}

// ---------------- normalization over S ----------------
__global__ void kNorm1(const float* __restrict__ partG, float* __restrict__ normA) {
  const int b = blockIdx.x, f = threadIdx.x;  // 32 x 512; 16 GEMM2 blocks per batch
  float s = 0.f;
#pragma unroll
  for (int i = 0; i < 16; ++i) s += partG[(size_t)(b * 16 + i) * 512 + f];
  normA[b * 512 + f] = fmaxf(s, 1e-10f);
}

__global__ void kNorm2(float* __restrict__ out, const float* __restrict__ normA) {
  const size_t i4 = (size_t)blockIdx.x * blockDim.x + threadIdx.x;  // float4 index
  f32x4 v = ((const f32x4*)out)[i4];
  const int f4 = (int)(i4 & 127);
  const int b = (int)(i4 >> 17);
  f32x4 n = ((const f32x4*)normA)[b * 128 + f4];
  v[0] /= n[0]; v[1] /= n[1]; v[2] /= n[2]; v[3] /= n[3];
  ((f32x4*)out)[i4] = v;
}

// ---------------- launcher ----------------
extern "C" void kernel_launch(void* const* d_in, const int* in_sizes, int n_in,
                              void* d_out, int out_size, void* d_ws, size_t ws_size,
                              hipStream_t stream) {
  const float* evid  = (const float*)d_in[0];   // [32,1024,512]
  const float* prior = (const float*)d_in[1];   // [32,1024,512]
  const float* W1    = (const float*)d_in[2];   // [512,1024]
  const float* b1    = (const float*)d_in[3];   // [512]
  const float* W2    = (const float*)d_in[4];   // [512,512]
  const float* b2    = (const float*)d_in[5];   // [512]
  float* out = (float*)d_out;

  char* ws = (char*)d_ws;
  char*   X2q   = ws;                              // 16,777,216 B (i8 [32768][512])
  char*   W1q   = ws + 16777216;                   //    524,288 B
  char*   W2q   = ws + 17301504;                   //    262,144 B
  float*  r1    = (float*)(ws + 17563648);         //    131,072 B
  float*  r2    = (float*)(ws + 17694720);         //    131,072 B
  double* part  = (double*)(ws + 17825792);        //      4,096 B (W1: 0-255, W2: 256-511)
  float*  wsv   = (float*)(ws + 17829888);         //        256 B
  float*  partG = (float*)(ws + 17830144);         //  1,048,576 B
  float*  normA = (float*)(ws + 18878720);         //     65,536 B (total ~18.9 MB)

  // X1q (i8 [32768][1024] = 33.5 MB) lives in d_out (67 MB); dead before GEMM2 writes.
  char* X1q = (char*)d_out;

  kWabs<<<512, 256, 0, stream>>>(W1, W2, part);
  kWfin<<<2, 256, 0, stream>>>(part, wsv);
  kWq<<<3072, 256, 0, stream>>>(W1, W2, wsv, W1q, W2q);
  kQ1<<<4096, 512, 0, stream>>>(prior, evid, X1q, r1);
  kGemm<1024, true><<<512, 512, 0, stream>>>(X1q, W1q, b1, r1, wsv + 0,
                                             X2q, r2, nullptr, nullptr, nullptr);
  kGemm<512, false><<<512, 512, 0, stream>>>(X2q, W2q, b2, r2, wsv + 1,
                                             nullptr, nullptr, prior, out, partG);
  kNorm1<<<32, 512, 0, stream>>>(partG, normA);
  kNorm2<<<16384, 256, 0, stream>>>(out, normA);
}